// Round 1
// baseline (1301.988 us; speedup 1.0000x reference)
//
#include <hip/hip_runtime.h>

// GCN 2-layer + mean-pool + linear readout, restructured:
//   h1[n] = relu( (norm_in[n] * scatter_dst(norm_out[src]*x[src])) @ W1 + b1 )
//   out   = ((1/N) * sum_u c[u]*h1[u]) @ W2 + b2  ... @ Wr^T + br
//   c[u]  = norm_out[u] * sum_{e: src[e]=u} norm_in[dst[e]]
// Layer 2's full 96-wide scatter collapses to scalar weights c[u].

constexpr int NN = 50000;
constexpr int NE = 800000;

// ws layout (floats):
//   0       deg_out[50000]
//   50000   deg_in [50000]
//   100000  norm_out[50000]
//   150000  norm_in [50000]
//   200000  c_raw  [50000]
//   250000  s      [96]
//   250112  agg1   [50000*96]
// total = 5,050,112 floats = 20,200,448 bytes

__global__ void k_deg(const int* __restrict__ src, const int* __restrict__ dst,
                      float* __restrict__ deg_out, float* __restrict__ deg_in) {
  int e = blockIdx.x * blockDim.x + threadIdx.x;
  if (e < NE) {
    atomicAdd(&deg_out[src[e]], 1.0f);
    atomicAdd(&deg_in[dst[e]], 1.0f);
  }
}

__global__ void k_norm(const float* __restrict__ deg_out, const float* __restrict__ deg_in,
                       float* __restrict__ norm_out, float* __restrict__ norm_in) {
  int n = blockIdx.x * blockDim.x + threadIdx.x;
  if (n < NN) {
    norm_out[n] = 1.0f / sqrtf(fmaxf(deg_out[n], 1.0f));
    norm_in[n]  = 1.0f / sqrtf(fmaxf(deg_in[n], 1.0f));
  }
}

// One thread per (edge, float4-slot): 24 slots cover the 96-f32 row.
// Lanes of a wave share an edge in groups of 24 -> index/norm loads broadcast,
// float4 gathers are row-coalesced. Scatter = 4 f32 atomics into agg1[dst].
// Slot 0 also accumulates the layer-2 scalar weight c_raw[src] += norm_in[dst].
__global__ void k_agg(const int* __restrict__ src, const int* __restrict__ dst,
                      const float* __restrict__ feats,
                      const float* __restrict__ norm_out, const float* __restrict__ norm_in,
                      float* __restrict__ agg1, float* __restrict__ c_raw) {
  int t = blockIdx.x * blockDim.x + threadIdx.x;
  if (t >= NE * 24) return;
  int e = t / 24;
  int q = t - e * 24;
  int s = src[e], d = dst[e];
  float w = norm_out[s];
  const float4 f = ((const float4*)feats)[s * 24 + q];
  float* arow = agg1 + (size_t)d * 96 + q * 4;
  atomicAdd(arow + 0, w * f.x);
  atomicAdd(arow + 1, w * f.y);
  atomicAdd(arow + 2, w * f.z);
  atomicAdd(arow + 3, w * f.w);
  if (q == 0) atomicAdd(&c_raw[s], norm_in[d]);
}

// Fused: v = norm_in[n]*agg1[n,:]; h = relu(v@W1 + b1); s += (norm_out[n]*c_raw[n])*h
// W1 staged in LDS (36 KB). 192 of 256 threads active: slot=tid/96 picks one of
// 2 nodes per iteration, col=tid%96 the output column. Per-thread register
// accumulator over all its nodes; one atomicAdd per thread at the end.
__global__ void k_mm(const float* __restrict__ agg1,
                     const float* __restrict__ norm_in, const float* __restrict__ norm_out,
                     const float* __restrict__ c_raw,
                     const float* __restrict__ W1, const float* __restrict__ b1,
                     float* __restrict__ svec) {
  __shared__ float W1s[96 * 96];
  __shared__ float v[2][96];
  int tid = threadIdx.x;
  for (int i = tid; i < 96 * 96; i += 256) W1s[i] = W1[i];
  __syncthreads();

  int slot = tid / 96;      // 0,1 active; 2 idle
  int col  = tid - slot * 96;
  float acc_s = 0.0f;

  for (int n0 = blockIdx.x * 2; n0 < NN; n0 += gridDim.x * 2) {
    int n = n0 + slot;
    if (slot < 2 && n < NN) v[slot][col] = agg1[(size_t)n * 96 + col] * norm_in[n];
    __syncthreads();
    if (slot < 2 && n < NN) {
      float acc = b1[col];
#pragma unroll 8
      for (int k = 0; k < 96; ++k)
        acc = fmaf(v[slot][k], W1s[k * 96 + col], acc);   // v: LDS broadcast; W1s: 2-way (free)
      float h = fmaxf(acc, 0.0f);
      acc_s += (norm_out[n] * c_raw[n]) * h;
    }
    __syncthreads();
  }
  if (slot < 2) atomicAdd(&svec[col], acc_s);
}

// hg = (s/N) @ W2 + b2 ; out = hg @ Wr^T + br   (trivial, one block)
__global__ void k_final(const float* __restrict__ svec,
                        const float* __restrict__ W2, const float* __restrict__ b2,
                        const float* __restrict__ Wr, const float* __restrict__ br,
                        float* __restrict__ out) {
  __shared__ float hg[96];
  int j = threadIdx.x;
  if (j < 96) {
    float acc = b2[j];
    const float invN = 1.0f / (float)NN;
    for (int k = 0; k < 96; ++k)
      acc = fmaf(svec[k] * invN, W2[k * 96 + j], acc);
    hg[j] = acc;
  }
  __syncthreads();
  if (j < 8) {
    float acc = br[j];
    for (int k = 0; k < 96; ++k)
      acc = fmaf(hg[k], Wr[j * 96 + k], acc);
    out[j] = acc;
  }
}

extern "C" void kernel_launch(void* const* d_in, const int* in_sizes, int n_in,
                              void* d_out, int out_size, void* d_ws, size_t ws_size,
                              hipStream_t stream) {
  const float* feats = (const float*)d_in[0];
  const int*   src   = (const int*)d_in[1];
  const int*   dst   = (const int*)d_in[2];
  const float* W1    = (const float*)d_in[3];
  const float* b1    = (const float*)d_in[4];
  const float* W2    = (const float*)d_in[5];
  const float* b2    = (const float*)d_in[6];
  const float* Wr    = (const float*)d_in[7];
  const float* br    = (const float*)d_in[8];
  float* out = (float*)d_out;

  float* ws       = (float*)d_ws;
  float* deg_out  = ws;
  float* deg_in   = ws + 50000;
  float* norm_out = ws + 100000;
  float* norm_in  = ws + 150000;
  float* c_raw    = ws + 200000;
  float* svec     = ws + 250000;
  float* agg1     = ws + 250112;

  size_t zero_bytes = (size_t)(250112 + (size_t)NN * 96) * sizeof(float);
  hipMemsetAsync(d_ws, 0, zero_bytes, stream);

  k_deg<<<(NE + 255) / 256, 256, 0, stream>>>(src, dst, deg_out, deg_in);
  k_norm<<<(NN + 255) / 256, 256, 0, stream>>>(deg_out, deg_in, norm_out, norm_in);
  k_agg<<<(NE * 24 + 255) / 256, 256, 0, stream>>>(src, dst, feats, norm_out, norm_in,
                                                   agg1, c_raw);
  k_mm<<<512, 256, 0, stream>>>(agg1, norm_in, norm_out, c_raw, W1, b1, svec);
  k_final<<<1, 128, 0, stream>>>(svec, W2, b2, Wr, br, out);
}

// Round 2
// 576.251 us; speedup vs baseline: 2.2594x; 2.2594x over previous
//
#include <hip/hip_runtime.h>

// GCN 2-layer + mean-pool + readout, CSR-gather formulation (no wide atomics):
//   h1[n] = relu( norm_in[n] * (sum_{e:dst=n} norm_out[src_e]*x[src_e]) @ W1 + b1 )
//   out   = ((1/N) * sum_u c[u]*h1[u]) @ W2 + b2  @ Wr^T + br
//   c[u]  = norm_out[u] * sum_{e:src=u} norm_in[dst_e]
//
// Pipeline: k_deg (int histograms) -> k_norm -> k_scan (row_ptr) ->
//           k_scatter (counting sort by dst, + c_raw) ->
//           k_fused (gather + W1 matmul + relu + weighted sum, all in one) ->
//           k_final (two tiny matvecs).

constexpr int NN = 50000;
constexpr int NE = 800000;

// ws layout in 4-byte units:
constexpr int OFF_DEG_OUT  = 0;       // int[50000]   (zeroed)
constexpr int OFF_DEG_IN   = 50000;   // int[50000]   (zeroed)
constexpr int OFF_CURSOR   = 100000;  // int[50000]   (zeroed)
constexpr int OFF_CRAW     = 150000;  // float[50000] (zeroed)
constexpr int OFF_SVEC     = 200000;  // float[256]   (zeroed)
constexpr int OFF_NORM_OUT = 200256;  // float[50000]
constexpr int OFF_NORM_IN  = 250256;  // float[50000]
constexpr int OFF_ROW_PTR  = 300256;  // int[50001]
constexpr int OFF_EDGE_SRC = 350272;  // int[800000]
constexpr size_t ZERO_BYTES = (size_t)(OFF_SVEC + 256) * 4;

__global__ void k_deg(const int* __restrict__ src, const int* __restrict__ dst,
                      int* __restrict__ deg_out, int* __restrict__ deg_in) {
  int e = blockIdx.x * blockDim.x + threadIdx.x;
  if (e < NE) {
    atomicAdd(&deg_out[src[e]], 1);
    atomicAdd(&deg_in[dst[e]], 1);
  }
}

__global__ void k_norm(const int* __restrict__ deg_out, const int* __restrict__ deg_in,
                       float* __restrict__ norm_out, float* __restrict__ norm_in) {
  int n = blockIdx.x * blockDim.x + threadIdx.x;
  if (n < NN) {
    norm_out[n] = 1.0f / sqrtf((float)max(deg_out[n], 1));
    norm_in[n]  = 1.0f / sqrtf((float)max(deg_in[n], 1));
  }
}

// Exclusive prefix sum of deg_in -> row_ptr[0..NN], single block of 256.
__global__ void k_scan(const int* __restrict__ deg_in, int* __restrict__ row_ptr) {
  __shared__ int part[256];
  const int CH = 196;               // 196*256 = 50176 >= NN
  int t = threadIdx.x;
  int base = t * CH;
  int s = 0;
  for (int i = 0; i < CH; ++i) {
    int idx = base + i;
    if (idx < NN) s += deg_in[idx];
  }
  part[t] = s;
  __syncthreads();
  for (int off = 1; off < 256; off <<= 1) {   // Hillis-Steele inclusive scan
    int v = (t >= off) ? part[t - off] : 0;
    __syncthreads();
    part[t] += v;
    __syncthreads();
  }
  int run = part[t] - s;            // exclusive prefix for this chunk
  for (int i = 0; i < CH; ++i) {
    int idx = base + i;
    if (idx < NN) { row_ptr[idx] = run; run += deg_in[idx]; }
  }
  if (t == 255) row_ptr[NN] = part[255];
}

// Counting-sort edges by dst; also accumulate layer-2 scalar weight c_raw.
__global__ void k_scatter(const int* __restrict__ src, const int* __restrict__ dst,
                          const int* __restrict__ row_ptr, int* __restrict__ cursor,
                          const float* __restrict__ norm_in,
                          int* __restrict__ edge_src, float* __restrict__ c_raw) {
  int e = blockIdx.x * blockDim.x + threadIdx.x;
  if (e < NE) {
    int d = dst[e], s = src[e];
    int pos = row_ptr[d] + atomicAdd(&cursor[d], 1);
    edge_src[pos] = s;
    atomicAdd(&c_raw[s], norm_in[d]);
  }
}

// Fused: CSR gather (32 lanes per node, NT=4 nodes per group) -> v regs,
// v @ W1 (W1 in LDS, v broadcast via width-32 shfl) -> relu -> svec += c[n]*h.
#define NT 4
__global__ __launch_bounds__(256, 4)
void k_fused(const float* __restrict__ feats,
             const float* __restrict__ norm_out, const float* __restrict__ norm_in,
             const float* __restrict__ c_raw,
             const int* __restrict__ row_ptr, const int* __restrict__ edge_src,
             const float* __restrict__ W1, const float* __restrict__ b1,
             float* __restrict__ svec) {
  __shared__ float W1s[96 * 96];
  __shared__ float b1s[96];
  __shared__ float red[96];
  int tid = threadIdx.x;
  for (int i = tid; i < 96 * 96 / 4; i += 256)
    ((float4*)W1s)[i] = ((const float4*)W1)[i];
  if (tid < 96) { b1s[tid] = b1[tid]; red[tid] = 0.0f; }
  __syncthreads();

  const int g = tid >> 5;           // half-wave group 0..7
  const int l = tid & 31;           // lane in group
  float accs0 = 0.f, accs1 = 0.f, accs2 = 0.f;

  const int NTILES = (NN + NT - 1) / NT;   // 12500
  const int tstride = gridDim.x * 8;

  for (int tile = blockIdx.x * 8 + g; tile < NTILES; tile += tstride) {
    float v[NT][3];
#pragma unroll
    for (int j = 0; j < NT; ++j) { v[j][0] = v[j][1] = v[j][2] = 0.f; }

    // ---- gather phase ----
#pragma unroll
    for (int j = 0; j < NT; ++j) {
      int n = tile * NT + j;
      if (n < NN) {
        int e0 = row_ptr[n], e1 = row_ptr[n + 1];
        for (int base = e0; base < e1; base += 32) {
          int idx = base + l;
          int es = 0; float w = 0.f;
          if (idx < e1) { es = edge_src[idx]; w = norm_out[es]; }
          int cnt = min(32, e1 - base);
          int t2 = 0;
          for (; t2 + 1 < cnt; t2 += 2) {     // 2-edge unroll: 6 loads in flight
            int   s0 = __shfl(es, t2, 32),     s1 = __shfl(es, t2 + 1, 32);
            float w0 = __shfl(w,  t2, 32),     w1 = __shfl(w,  t2 + 1, 32);
            const float* r0 = feats + (size_t)s0 * 96;
            const float* r1 = feats + (size_t)s1 * 96;
            float a0 = r0[l], a1 = r0[l + 32], a2 = r0[l + 64];
            float c0 = r1[l], c1 = r1[l + 32], c2 = r1[l + 64];
            v[j][0] = fmaf(w0, a0, fmaf(w1, c0, v[j][0]));
            v[j][1] = fmaf(w0, a1, fmaf(w1, c1, v[j][1]));
            v[j][2] = fmaf(w0, a2, fmaf(w1, c2, v[j][2]));
          }
          if (t2 < cnt) {
            int   s0 = __shfl(es, t2, 32);
            float w0 = __shfl(w,  t2, 32);
            const float* r0 = feats + (size_t)s0 * 96;
            v[j][0] = fmaf(w0, r0[l],      v[j][0]);
            v[j][1] = fmaf(w0, r0[l + 32], v[j][1]);
            v[j][2] = fmaf(w0, r0[l + 64], v[j][2]);
          }
        }
        float ni = norm_in[n];
        v[j][0] *= ni; v[j][1] *= ni; v[j][2] *= ni;
      }
    }

    // ---- matmul + relu + weighted sum ----
    float h[NT][3];
#pragma unroll
    for (int j = 0; j < NT; ++j) {
      h[j][0] = b1s[l]; h[j][1] = b1s[l + 32]; h[j][2] = b1s[l + 64];
    }
#pragma unroll
    for (int kb = 0; kb < 3; ++kb) {
#pragma unroll
      for (int kk = 0; kk < 32; ++kk) {
        int k = kb * 32 + kk;
        float w0 = W1s[k * 96 + l];
        float w1 = W1s[k * 96 + l + 32];
        float w2 = W1s[k * 96 + l + 64];
#pragma unroll
        for (int j = 0; j < NT; ++j) {
          float vk = __shfl(v[j][kb], kk, 32);
          h[j][0] = fmaf(vk, w0, h[j][0]);
          h[j][1] = fmaf(vk, w1, h[j][1]);
          h[j][2] = fmaf(vk, w2, h[j][2]);
        }
      }
    }
#pragma unroll
    for (int j = 0; j < NT; ++j) {
      int n = tile * NT + j;
      if (n < NN) {
        float cw = norm_out[n] * c_raw[n];
        accs0 += cw * fmaxf(h[j][0], 0.f);
        accs1 += cw * fmaxf(h[j][1], 0.f);
        accs2 += cw * fmaxf(h[j][2], 0.f);
      }
    }
  }

  atomicAdd(&red[l],      accs0);   // LDS reduce across the block
  atomicAdd(&red[l + 32], accs1);
  atomicAdd(&red[l + 64], accs2);
  __syncthreads();
  if (tid < 96) atomicAdd(&svec[tid], red[tid]);
}

// hg = (svec/N) @ W2 + b2 ; out = hg @ Wr^T + br
__global__ void k_final(const float* __restrict__ svec,
                        const float* __restrict__ W2, const float* __restrict__ b2,
                        const float* __restrict__ Wr, const float* __restrict__ br,
                        float* __restrict__ out) {
  __shared__ float hg[96];
  int j = threadIdx.x;
  if (j < 96) {
    float acc = b2[j];
    const float invN = 1.0f / (float)NN;
    for (int k = 0; k < 96; ++k)
      acc = fmaf(svec[k] * invN, W2[k * 96 + j], acc);
    hg[j] = acc;
  }
  __syncthreads();
  if (j < 8) {
    float acc = br[j];
    for (int k = 0; k < 96; ++k)
      acc = fmaf(hg[k], Wr[j * 96 + k], acc);
    out[j] = acc;
  }
}

extern "C" void kernel_launch(void* const* d_in, const int* in_sizes, int n_in,
                              void* d_out, int out_size, void* d_ws, size_t ws_size,
                              hipStream_t stream) {
  const float* feats = (const float*)d_in[0];
  const int*   src   = (const int*)d_in[1];
  const int*   dst   = (const int*)d_in[2];
  const float* W1    = (const float*)d_in[3];
  const float* b1    = (const float*)d_in[4];
  const float* W2    = (const float*)d_in[5];
  const float* b2    = (const float*)d_in[6];
  const float* Wr    = (const float*)d_in[7];
  const float* br    = (const float*)d_in[8];
  float* out = (float*)d_out;

  int*   wsi      = (int*)d_ws;
  float* wsf      = (float*)d_ws;
  int*   deg_out  = wsi + OFF_DEG_OUT;
  int*   deg_in   = wsi + OFF_DEG_IN;
  int*   cursor   = wsi + OFF_CURSOR;
  float* c_raw    = wsf + OFF_CRAW;
  float* svec     = wsf + OFF_SVEC;
  float* norm_out = wsf + OFF_NORM_OUT;
  float* norm_in  = wsf + OFF_NORM_IN;
  int*   row_ptr  = wsi + OFF_ROW_PTR;
  int*   edge_src = wsi + OFF_EDGE_SRC;

  hipMemsetAsync(d_ws, 0, ZERO_BYTES, stream);

  k_deg<<<(NE + 255) / 256, 256, 0, stream>>>(src, dst, deg_out, deg_in);
  k_norm<<<(NN + 255) / 256, 256, 0, stream>>>(deg_out, deg_in, norm_out, norm_in);
  k_scan<<<1, 256, 0, stream>>>(deg_in, row_ptr);
  k_scatter<<<(NE + 255) / 256, 256, 0, stream>>>(src, dst, row_ptr, cursor,
                                                  norm_in, edge_src, c_raw);
  k_fused<<<1024, 256, 0, stream>>>(feats, norm_out, norm_in, c_raw,
                                    row_ptr, edge_src, W1, b1, svec);
  k_final<<<1, 128, 0, stream>>>(svec, W2, b2, Wr, br, out);
}